// Round 2
// baseline (20422.423 us; speedup 1.0000x reference)
//
#include <hip/hip_runtime.h>
#include <hip/hip_cooperative_groups.h>
#include <math.h>

namespace cg = cooperative_groups;

#define HH 512   // hidden
#define DD 512   // embed dim
#define BB 64    // batch (== one wave)
#define SS 256   // seq len
#define KK 1024  // D+H
#define CC 5

// ---------------------------------------------------------------------------
// Gather embeddings, transposed to [s][d][b] so recurrence loads are coalesced
// along b (64 lanes = 64 batch elems = one 256B segment per k).
// ---------------------------------------------------------------------------
__global__ __launch_bounds__(256)
void gather_embed_k(const int* __restrict__ x, const float* __restrict__ embed,
                    float* __restrict__ xeT)
{
    const int s   = blockIdx.x;
    const int tid = threadIdx.x;
    const int b   = tid & 63;
    const int grp = tid >> 6;
    __shared__ int rows[BB];
    if (tid < BB) rows[tid] = x[tid * SS + s];   // x is [B][S]
    __syncthreads();
    const float* e = embed + (size_t)rows[b] * DD;
    float* o = xeT + (size_t)s * DD * BB + b;
    for (int d = grp * 128; d < grp * 128 + 128; ++d)
        o[(size_t)d * BB] = e[d];                // coalesced writes along b
}

__device__ __forceinline__ float sigmoidf_(float v) {
    return 1.0f / (1.0f + expf(-v));
}

// ---------------------------------------------------------------------------
// Cooperative recurrence. 512 WGs x 256 threads (2 WGs/CU, 2 waves/SIMD).
//   WG w: dir = w>>8, owns 2 h-values [h0, h0+2) -> 8 gate rows (4 gates x 2 h).
//   Weights for those 8 rows (8 x 1024 fp32 = 32 KB) are staged in LDS ONCE,
//   then reused across all 256 timesteps (wave-uniform ds_read_b128 broadcast).
//   Wave r (0..3): K-quarter. r<2: x-part halves, r>=2: h-part halves.
//   Lane = batch element; activation loads are coalesced 256B wave-loads.
//   One grid.sync() per timestep; h double-buffered by phase t&1.
// ---------------------------------------------------------------------------
__global__ __launch_bounds__(256)
void bilstm_recur_k(const float* __restrict__ xeT,
                    const float* __restrict__ fwd_W, const float* __restrict__ fwd_b,
                    const float* __restrict__ bwd_W, const float* __restrict__ bwd_b,
                    float* __restrict__ hbuf,   // [phase 2][dir 2][H][B]
                    float* __restrict__ hist)   // [dir 2][S][H][B]
{
    cg::grid_group grid = cg::this_grid();
    const int w     = blockIdx.x;
    const int dir   = w >> 8;
    const int slice = w & 255;
    const int h0    = slice << 1;          // 2 h-values per WG
    const int tid   = threadIdx.x;
    const int b     = tid & 63;
    const int r     = __builtin_amdgcn_readfirstlane(tid >> 6);

    const float* W  = dir ? bwd_W : fwd_W;
    const float* bi = dir ? bwd_b : fwd_b;

    __shared__ float wt[8 * KK];           // 32 KB: 8 gate rows x K=1024
    __shared__ float part[4][8][BB];       // 8 KB: per-wave partial preacts

    // ---- stage weights into LDS once (each wave copies 2 rows, float4) ----
    for (int row = r; row < 8; row += 4) {
        const int g  = row >> 1;
        const int hh = row & 1;
        const float4* src = reinterpret_cast<const float4*>(
            W + ((size_t)g * HH + h0 + hh) * KK);
        float4* dst = reinterpret_cast<float4*>(wt + row * KK);
        for (int j = b; j < KK / 4; j += 64) dst[j] = src[j];
    }

    const int kglob = r << 8;              // 0,256,512,768
    const int isH   = kglob >> 9;          // 0: x columns, 1: h columns
    const int koff  = kglob & 511;         // offset within that 512-range
    const float4* wt4 = reinterpret_cast<const float4*>(wt);

    // zero h(t=0), phase 0
    if (tid < 2 * BB)
        hbuf[((size_t)(0 * 2 + dir) * HH + h0 + (tid >> 6)) * BB + (tid & 63)] = 0.0f;
    __syncthreads();
    grid.sync();

    for (int t = 0; t < SS; ++t) {
        const int s = dir ? (SS - 1 - t) : t;
        const float* col = isH ? (hbuf + (size_t)((t & 1) * 2 + dir) * HH * BB)
                               : (xeT + (size_t)s * DD * BB);
        const float* cb = col + (size_t)koff * BB + b;

        float acc[8];
        #pragma unroll
        for (int i = 0; i < 8; ++i) acc[i] = 0.0f;

        #pragma unroll 4
        for (int kk = 0; kk < 256; kk += 4) {
            const float v0 = cb[(size_t)(kk + 0) * BB];
            const float v1 = cb[(size_t)(kk + 1) * BB];
            const float v2 = cb[(size_t)(kk + 2) * BB];
            const float v3 = cb[(size_t)(kk + 3) * BB];
            #pragma unroll
            for (int row = 0; row < 8; ++row) {
                const float4 wv = wt4[(row * KK + kglob + kk) >> 2]; // uniform bcast
                acc[row] = fmaf(v0, wv.x, acc[row]);
                acc[row] = fmaf(v1, wv.y, acc[row]);
                acc[row] = fmaf(v2, wv.z, acc[row]);
                acc[row] = fmaf(v3, wv.w, acc[row]);
            }
        }

        #pragma unroll
        for (int i = 0; i < 8; ++i) part[r][i][b] = acc[i];
        __syncthreads();

        // combine: threads 0..127 -> (hh = tid>>6, b); sum 4 partials + bias
        if (tid < 128) {
            const int hh = tid >> 6;
            const int bb = tid & 63;
            float pg[4];
            #pragma unroll
            for (int g = 0; g < 4; ++g) {
                const int row = g * 2 + hh;
                pg[g] = part[0][row][bb] + part[1][row][bb] +
                        part[2][row][bb] + part[3][row][bb] +
                        bi[g * HH + h0 + hh];
            }
            const float f  = sigmoidf_(pg[0]);
            const float i_ = sigmoidf_(pg[1]);
            const float ct = tanhf(pg[2]);
            const float o  = sigmoidf_(pg[3]);
            const float c  = (f + i_) * ct;   // faithful: prev cell state unused
            const float hn = o * tanhf(c);
            const int h = h0 + hh;
            hbuf[((size_t)(((t & 1) ^ 1) * 2 + dir) * HH + h) * BB + bb] = hn;
            hist[(((size_t)dir * SS + s) * HH + h) * BB + bb] = hn;
        }
        grid.sync();
    }
}

// ---------------------------------------------------------------------------
// pooled[h][b] = max_s tanh(hf[s][h][b] * hb[s][h][b])
// ---------------------------------------------------------------------------
__global__ __launch_bounds__(256)
void pool_k(const float* __restrict__ hist, float* __restrict__ pooled)
{
    const int i = blockIdx.x * 256 + threadIdx.x;  // i = h*64 + b, 0..32767
    float m = -2.0f;
    for (int s = 0; s < SS; ++s) {
        const float a = hist[(size_t)s * (HH * BB) + i];
        const float c = hist[(size_t)(SS + s) * (HH * BB) + i];
        m = fmaxf(m, tanhf(a * c));
    }
    pooled[i] = m;
}

// ---------------------------------------------------------------------------
// out[b][c] = sum_h pooled[h][b] * Wout[c][h] + bout[c]
// ---------------------------------------------------------------------------
__global__ __launch_bounds__(256)
void outgemm_k(const float* __restrict__ pooled, const float* __restrict__ Wout,
               const float* __restrict__ bout, float* __restrict__ out)
{
    const int c   = blockIdx.x;
    const int tid = threadIdx.x;
    const int b   = tid & 63;
    const int q   = __builtin_amdgcn_readfirstlane(tid >> 6);
    float p = 0.0f;
    for (int j = 0; j < 128; ++j) {
        const int h = q * 128 + j;
        p = fmaf(pooled[(size_t)h * BB + b], Wout[c * HH + h], p);
    }
    __shared__ float red[4][BB];
    red[q][b] = p;
    __syncthreads();
    if (tid < BB)
        out[tid * CC + c] = red[0][tid] + red[1][tid] + red[2][tid] + red[3][tid] + bout[c];
}

// ---------------------------------------------------------------------------
extern "C" void kernel_launch(void* const* d_in, const int* in_sizes, int n_in,
                              void* d_out, int out_size, void* d_ws, size_t ws_size,
                              hipStream_t stream)
{
    const int*   x     = (const int*)d_in[0];
    const float* embed = (const float*)d_in[1];
    const float* fwd_W = (const float*)d_in[2];
    const float* fwd_b = (const float*)d_in[3];
    const float* bwd_W = (const float*)d_in[4];
    const float* bwd_b = (const float*)d_in[5];
    const float* Wout  = (const float*)d_in[6];
    const float* bout  = (const float*)d_in[7];
    float* out = (float*)d_out;

    // workspace carve-up (floats): total ~25.3M floats ~= 101.3 MB
    float* ws     = (float*)d_ws;
    float* xeT    = ws;                                  // S*D*B   = 8,388,608
    float* hist   = xeT  + (size_t)SS * DD * BB;         // 2*S*H*B = 16,777,216
    float* hbuf   = hist + (size_t)2 * SS * HH * BB;     // 2*2*H*B = 131,072
    float* pooled = hbuf + (size_t)2 * 2 * HH * BB;      // H*B     = 32,768

    gather_embed_k<<<SS, 256, 0, stream>>>(x, embed, xeT);

    void* args[] = {(void*)&xeT, (void*)&fwd_W, (void*)&fwd_b, (void*)&bwd_W,
                    (void*)&bwd_b, (void*)&hbuf, (void*)&hist};
    hipLaunchCooperativeKernel((void*)bilstm_recur_k, dim3(512), dim3(256),
                               args, 0, stream);

    pool_k<<<128, 256, 0, stream>>>(hist, pooled);
    outgemm_k<<<CC, 256, 0, stream>>>(pooled, Wout, bout, out);
}

// Round 3
// 19061.691 us; speedup vs baseline: 1.0714x; 1.0714x over previous
//
#include <hip/hip_runtime.h>
#include <math.h>

#define HH 512
#define DD 512
#define BB 64
#define SS 256
#define KK 1024
#define CC 5

typedef __attribute__((ext_vector_type(8))) short short8;
typedef __attribute__((ext_vector_type(4))) float float4v;

// ---- workspace layout (bytes) ----
#define OFF_WFRAG   0u
#define SZ_WFRAG    16777216u            // 256 slices x 2 sp x 32 kt x 64 lane x 8 bf16
#define OFF_HTHI    16777216u
#define SZ_HT       262144u              // 2 phase x 2 dir x 64 b x 512 k bf16
#define OFF_HTLO    17039360u
#define OFF_CNT     17301504u            // 128 B (cnt[dir] at dword dir*32)
#define OFF_HIST    17301632u            // 2 x 256 x 512 x 64 fp32 = 67,108,864
#define OFF_POOLED  84410496u            // 512*64 fp32

__device__ __forceinline__ unsigned f2bf_bits(float f) {
    unsigned u = __builtin_bit_cast(unsigned, f);
    return (u + 0x7fffu + ((u >> 16) & 1u)) >> 16;   // RNE
}

// ---------------------------------------------------------------------------
// Pack W into MFMA A-fragment layout, split hi/lo bf16.
// wfrag[slice][sp][kt][lane][j] = split_sp( W[g(m)*512+h0+hh(m)][kt*32+quad*8+j] )
//   m = lane&15, quad = lane>>4, g = m>>2, hh = m&3, h0 = (slice&127)*4.
// ---------------------------------------------------------------------------
__global__ __launch_bounds__(256)
void wpack_k(const float* __restrict__ fwd_W, const float* __restrict__ bwd_W,
             short* __restrict__ wfrag)
{
    const int slice = blockIdx.x;           // 0..255
    const int dir   = slice >> 7;
    const int h0    = (slice & 127) << 2;
    const int tid   = threadIdx.x;
    const int lane  = tid & 63;
    const int ktq   = tid >> 6;             // 0..3
    const int m     = lane & 15;
    const int quad  = lane >> 4;
    const int g     = m >> 2;
    const int hh    = m & 3;
    const float* W  = dir ? bwd_W : fwd_W;
    const float* row = W + ((size_t)g * HH + h0 + hh) * KK + quad * 8;
    short8* dst = (short8*)wfrag + (size_t)slice * (2 * 32 * 64);

    for (int pass = 0; pass < 8; ++pass) {
        const int kt = pass * 4 + ktq;
        const float* src = row + kt * 32;
        short8 vhi, vlo;
        #pragma unroll
        for (int j = 0; j < 8; ++j) {
            const float f = src[j];
            const unsigned hib = f2bf_bits(f);
            const float hif = __builtin_bit_cast(float, hib << 16);
            const unsigned lob = f2bf_bits(f - hif);
            vhi[j] = (short)hib;
            vlo[j] = (short)lob;
        }
        dst[(0 * 32 + kt) * 64 + lane] = vhi;
        dst[(1 * 32 + kt) * 64 + lane] = vlo;
    }
}

// ---------------------------------------------------------------------------
__global__ __launch_bounds__(256)
void zero_k(unsigned* __restrict__ base, int ndw)
{
    int i = blockIdx.x * 256 + threadIdx.x;
    const int stride = gridDim.x * 256;
    for (; i < ndw; i += stride) base[i] = 0u;
}

// ---------------------------------------------------------------------------
// Cooperative recurrence: 256 WGs x 256 thr (1 WG/CU, 4 waves).
//   WG w: dir = w>>7, owns 4 h-values (16 gate rows). Wave r: batch n-tile r.
//   Per step: x-part MFMA (no dep) -> per-dir barrier spin -> h-part MFMA
//   -> bias + per-wave LDS exchange -> nonlinearity -> publish h (bf16 hi/lo)
//   -> fence + wave arrival.
// ---------------------------------------------------------------------------
__global__ void __launch_bounds__(256, 1)
bilstm_recur_k(const int* __restrict__ x, const float* __restrict__ embed,
               const float* __restrict__ fwd_b, const float* __restrict__ bwd_b,
               const short* __restrict__ wfrag,
               short* __restrict__ hT_hi, short* __restrict__ hT_lo,
               float* __restrict__ hist, unsigned* __restrict__ cnt)
{
    extern __shared__ char smem[];
    short8* wlds = (short8*)smem;                 // [2 sp][32 kt][64 lane] = 64 KB
    float*  ex   = (float*)(smem + 65536);        // [4 wave][16][16] = 4 KB

    const int w    = blockIdx.x;
    const int dir  = w >> 7;
    const int h0   = (w & 127) << 2;
    const int tid  = threadIdx.x;
    const int lane = tid & 63;
    const int wv   = __builtin_amdgcn_readfirstlane(tid >> 6);
    const int n0   = wv << 4;
    const int nn   = lane & 15;
    const int quad = lane >> 4;

    // stage this WG's W fragments into LDS once
    {
        const short8* src = (const short8*)wfrag + (size_t)w * (2 * 32 * 64);
        for (int i = tid; i < 2 * 32 * 64; i += 256) wlds[i] = src[i];
    }
    __syncthreads();

    const float* bi = dir ? bwd_b : fwd_b;
    // bias for this lane's 4 C-rows: rows quad*4+reg -> gate=quad, hh=reg
    const float4 biasv = *(const float4*)(bi + quad * HH + h0);
    const float bias_arr[4] = {biasv.x, biasv.y, biasv.z, biasv.w};

    unsigned* mycnt = cnt + dir * 32;
    float* exw = ex + wv * 256;

    for (int t = 0; t < SS; ++t) {
        const int s = dir ? (SS - 1 - t) : t;
        const int p = t & 1;

        float4v acc = {0.f, 0.f, 0.f, 0.f};

        // ---------- x-part (no dependency on h) ----------
        const int erow = x[(n0 + nn) * SS + s];          // x is [B][S]
        const float* eb = embed + (size_t)erow * DD + quad * 8;
        #pragma unroll
        for (int kt = 0; kt < 16; ++kt) {
            const float4 e0 = *(const float4*)(eb + kt * 32);
            const float4 e1 = *(const float4*)(eb + kt * 32 + 4);
            const float ev[8] = {e0.x, e0.y, e0.z, e0.w, e1.x, e1.y, e1.z, e1.w};
            short8 xhi, xlo;
            #pragma unroll
            for (int j = 0; j < 8; ++j) {
                const unsigned hib = f2bf_bits(ev[j]);
                const float hif = __builtin_bit_cast(float, hib << 16);
                const unsigned lob = f2bf_bits(ev[j] - hif);
                xhi[j] = (short)hib;
                xlo[j] = (short)lob;
            }
            const short8 whi = wlds[(0 * 32 + kt) * 64 + lane];
            const short8 wlo = wlds[(1 * 32 + kt) * 64 + lane];
            acc = __builtin_amdgcn_mfma_f32_16x16x32_bf16(whi, xhi, acc, 0, 0, 0);
            acc = __builtin_amdgcn_mfma_f32_16x16x32_bf16(whi, xlo, acc, 0, 0, 0);
            acc = __builtin_amdgcn_mfma_f32_16x16x32_bf16(wlo, xhi, acc, 0, 0, 0);
        }

        // ---------- wait for h(t-1) of this direction ----------
        if (t > 0) {
            const unsigned tgt = (unsigned)(512 * t);
            while (__hip_atomic_load(mycnt, __ATOMIC_RELAXED,
                                     __HIP_MEMORY_SCOPE_AGENT) < tgt) {
                __builtin_amdgcn_s_sleep(1);
            }
            __threadfence();   // acquire: invalidate stale L1/L2 before h reads
        }

        // ---------- h-part ----------
        const size_t hbase = ((size_t)(p * 2 + dir) * BB + n0 + nn) * 64 + quad;
        const short8* hhi = (const short8*)hT_hi + hbase;
        const short8* hlo = (const short8*)hT_lo + hbase;
        #pragma unroll
        for (int kt = 0; kt < 16; ++kt) {
            const short8 zhi = hhi[kt * 4];
            const short8 zlo = hlo[kt * 4];
            const short8 whi = wlds[(0 * 32 + 16 + kt) * 64 + lane];
            const short8 wlo = wlds[(1 * 32 + 16 + kt) * 64 + lane];
            acc = __builtin_amdgcn_mfma_f32_16x16x32_bf16(whi, zhi, acc, 0, 0, 0);
            acc = __builtin_amdgcn_mfma_f32_16x16x32_bf16(whi, zlo, acc, 0, 0, 0);
            acc = __builtin_amdgcn_mfma_f32_16x16x32_bf16(wlo, zhi, acc, 0, 0, 0);
        }

        // ---------- bias + per-wave exchange (C rows: gate=quad, hh=reg) ----------
        #pragma unroll
        for (int r2 = 0; r2 < 4; ++r2)
            exw[(quad * 4 + r2) * 16 + nn] = acc[r2] + bias_arr[r2];
        // same-wave LDS RAW: compiler inserts lgkmcnt wait
        float pg[4];
        #pragma unroll
        for (int g = 0; g < 4; ++g)
            pg[g] = exw[(g * 4 + quad) * 16 + nn];

        // lane now owns (h = h0+quad, b = n0+nn)
        const float f_  = 1.f / (1.f + expf(-pg[0]));
        const float i_  = 1.f / (1.f + expf(-pg[1]));
        const float ct  = tanhf(pg[2]);
        const float o_  = 1.f / (1.f + expf(-pg[3]));
        const float c_  = (f_ + i_) * ct;      // faithful: prev cell unused
        const float hn  = o_ * tanhf(c_);

        const int b = n0 + nn;
        const int h = h0 + quad;
        const unsigned hib = f2bf_bits(hn);
        const float hif = __builtin_bit_cast(float, hib << 16);
        const unsigned lob = f2bf_bits(hn - hif);
        const size_t hidx = ((size_t)((p ^ 1) * 2 + dir) * BB + b) * HH + h;
        hT_hi[hidx] = (short)hib;
        hT_lo[hidx] = (short)lob;
        hist[(((size_t)dir * SS + s) * HH + h) * BB + b] = hn;

        // ---------- publish: fence + wave arrival ----------
        __threadfence();   // release: drain stores, write back L2
        if (lane == 0)
            __hip_atomic_fetch_add(mycnt, 1u, __ATOMIC_RELAXED,
                                   __HIP_MEMORY_SCOPE_AGENT);
    }
}

// ---------------------------------------------------------------------------
__global__ __launch_bounds__(256)
void pool_k(const float* __restrict__ hist, float* __restrict__ pooled)
{
    const int i = blockIdx.x * 256 + threadIdx.x;   // i = h*64 + b
    float m = -2.0f;
    for (int s = 0; s < SS; ++s) {
        const float a = hist[(size_t)s * (HH * BB) + i];
        const float c = hist[(size_t)(SS + s) * (HH * BB) + i];
        m = fmaxf(m, tanhf(a * c));
    }
    pooled[i] = m;
}

__global__ __launch_bounds__(256)
void outgemm_k(const float* __restrict__ pooled, const float* __restrict__ Wout,
               const float* __restrict__ bout, float* __restrict__ out)
{
    const int c   = blockIdx.x;
    const int tid = threadIdx.x;
    const int b   = tid & 63;
    const int q   = __builtin_amdgcn_readfirstlane(tid >> 6);
    float p = 0.0f;
    for (int j = 0; j < 128; ++j) {
        const int h = q * 128 + j;
        p = fmaf(pooled[(size_t)h * BB + b], Wout[c * HH + h], p);
    }
    __shared__ float red[4][BB];
    red[q][b] = p;
    __syncthreads();
    if (tid < BB)
        out[tid * CC + c] = red[0][tid] + red[1][tid] + red[2][tid] + red[3][tid] + bout[c];
}

// ---------------------------------------------------------------------------
extern "C" void kernel_launch(void* const* d_in, const int* in_sizes, int n_in,
                              void* d_out, int out_size, void* d_ws, size_t ws_size,
                              hipStream_t stream)
{
    const int*   x     = (const int*)d_in[0];
    const float* embed = (const float*)d_in[1];
    const float* fwd_W = (const float*)d_in[2];
    const float* fwd_b = (const float*)d_in[3];
    const float* bwd_W = (const float*)d_in[4];
    const float* bwd_b = (const float*)d_in[5];
    const float* Wout  = (const float*)d_in[6];
    const float* bout  = (const float*)d_in[7];
    float* out = (float*)d_out;

    char* wsb = (char*)d_ws;
    short*    wfrag  = (short*)(wsb + OFF_WFRAG);
    short*    hT_hi  = (short*)(wsb + OFF_HTHI);
    short*    hT_lo  = (short*)(wsb + OFF_HTLO);
    unsigned* cnt    = (unsigned*)(wsb + OFF_CNT);
    float*    hist   = (float*)(wsb + OFF_HIST);
    float*    pooled = (float*)(wsb + OFF_POOLED);

    wpack_k<<<256, 256, 0, stream>>>(fwd_W, bwd_W, wfrag);
    // zero hT_hi + hT_lo + counters (contiguous region)
    zero_k<<<512, 256, 0, stream>>>((unsigned*)(wsb + OFF_HTHI),
                                    (int)((2 * SZ_HT + 128) / 4));

    hipFuncSetAttribute((const void*)bilstm_recur_k,
                        hipFuncAttributeMaxDynamicSharedMemorySize, 69632);
    void* args[] = {(void*)&x, (void*)&embed, (void*)&fwd_b, (void*)&bwd_b,
                    (void*)&wfrag, (void*)&hT_hi, (void*)&hT_lo,
                    (void*)&hist, (void*)&cnt};
    hipLaunchCooperativeKernel((void*)bilstm_recur_k, dim3(256), dim3(256),
                               args, 69632, stream);

    pool_k<<<128, 256, 0, stream>>>(hist, pooled);
    outgemm_k<<<CC, 256, 0, stream>>>(pooled, Wout, bout, out);
}

// Round 4
// 3590.746 us; speedup vs baseline: 5.6875x; 5.3086x over previous
//
#include <hip/hip_runtime.h>
#include <math.h>

#define HH 512
#define DD 512
#define BB 64
#define SS 256
#define KK 1024
#define CC 5

typedef __attribute__((ext_vector_type(8))) short short8;
typedef __attribute__((ext_vector_type(4))) float float4v;

// ---- workspace layout (bytes) ----
#define OFF_WFRAG   0u
#define SZ_WFRAG    16777216u            // 256 slices x 2 sp x 32 kt x 64 lane x 16B
#define OFF_HSPL    16777216u
#define SZ_HSPL     524288u              // [2 sp][2 phase][2 dir][64 b][512 k] shorts
#define OFF_FLG     17301504u            // 256 x 4B flags (flg[dir*128 + wg])
#define OFF_HIST    17302528u            // 2 x 256 x 512 x 64 fp32
#define OFF_POOLED  84411392u            // 512*64 fp32
#define HSPL_PLANE  131072               // shorts per split plane (2*2*64*512)

__device__ __forceinline__ unsigned f2bf_bits(float f) {
    unsigned u = __builtin_bit_cast(unsigned, f);
    return (u + 0x7fffu + ((u >> 16) & 1u)) >> 16;   // RNE
}

// ---------------------------------------------------------------------------
// Pack W into MFMA A-fragment layout, split hi/lo bf16.  (identical to R3)
// ---------------------------------------------------------------------------
__global__ __launch_bounds__(256)
void wpack_k(const float* __restrict__ fwd_W, const float* __restrict__ bwd_W,
             short* __restrict__ wfrag)
{
    const int slice = blockIdx.x;           // 0..255
    const int dir   = slice >> 7;
    const int h0    = (slice & 127) << 2;
    const int tid   = threadIdx.x;
    const int lane  = tid & 63;
    const int ktq   = tid >> 6;             // 0..3
    const int m     = lane & 15;
    const int quad  = lane >> 4;
    const int g     = m >> 2;
    const int hh    = m & 3;
    const float* W  = dir ? bwd_W : fwd_W;
    const float* row = W + ((size_t)g * HH + h0 + hh) * KK + quad * 8;
    short8* dst = (short8*)wfrag + (size_t)slice * (2 * 32 * 64);

    for (int pass = 0; pass < 8; ++pass) {
        const int kt = pass * 4 + ktq;
        const float* src = row + kt * 32;
        short8 vhi, vlo;
        #pragma unroll
        for (int j = 0; j < 8; ++j) {
            const float f = src[j];
            const unsigned hib = f2bf_bits(f);
            const float hif = __builtin_bit_cast(float, hib << 16);
            const unsigned lob = f2bf_bits(f - hif);
            vhi[j] = (short)hib;
            vlo[j] = (short)lob;
        }
        dst[(0 * 32 + kt) * 64 + lane] = vhi;
        dst[(1 * 32 + kt) * 64 + lane] = vlo;
    }
}

// ---------------------------------------------------------------------------
__global__ __launch_bounds__(256)
void zero_k(unsigned* __restrict__ base, int ndw)
{
    int i = blockIdx.x * 256 + threadIdx.x;
    const int stride = gridDim.x * 256;
    for (; i < ndw; i += stride) base[i] = 0u;
}

// ---------------------------------------------------------------------------
// Cooperative recurrence: 256 WGs x 256 thr (1 WG/CU).
//   Sync protocol (fence-free): h published via agent-scope write-through
//   atomic dword stores; per-WG flag store after vmcnt-drain + barrier;
//   waiters poll 128 flags (2 wave-loads + __any); h fragments read via
//   agent-scope 8B atomic loads (bypass stale per-XCD L2).
// ---------------------------------------------------------------------------
__global__ void __launch_bounds__(256, 1)
bilstm_recur_k(const int* __restrict__ x, const float* __restrict__ embed,
               const float* __restrict__ fwd_b, const float* __restrict__ bwd_b,
               const short* __restrict__ wfrag,
               short* __restrict__ hspl, float* __restrict__ hist,
               unsigned* __restrict__ flg)
{
    extern __shared__ char smem[];
    short8* wlds = (short8*)smem;                       // 64 KB W fragments
    float*  ex   = (float*)(smem + 65536);              // 4 KB exchange
    unsigned short* stg = (unsigned short*)(smem + 69632); // 1 KB publish stage

    const int w      = blockIdx.x;
    const int dir    = w >> 7;
    const int wlocal = w & 127;
    const int h0     = wlocal << 2;
    const int tid    = threadIdx.x;
    const int lane   = tid & 63;
    const int wv     = __builtin_amdgcn_readfirstlane(tid >> 6);
    const int n0     = wv << 4;
    const int nn     = lane & 15;
    const int quad   = lane >> 4;

    // stage this WG's W fragments into LDS once
    {
        const short8* src = (const short8*)wfrag + (size_t)w * (2 * 32 * 64);
        for (int i = tid; i < 2 * 32 * 64; i += 256) wlds[i] = src[i];
    }
    __syncthreads();

    const float* bi = dir ? bwd_b : fwd_b;
    const float4 biasv = *(const float4*)(bi + quad * HH + h0);
    const float bias_arr[4] = {biasv.x, biasv.y, biasv.z, biasv.w};

    unsigned* myflg = flg + dir * 128;
    float* exw = ex + wv * 256;
    const int b = n0 + nn;
    const int h = h0 + quad;

    for (int t = 0; t < SS; ++t) {
        const int s = dir ? (SS - 1 - t) : t;
        const int p = t & 1;

        float4v acc = {0.f, 0.f, 0.f, 0.f};

        // ---------- x-part (independent of h; overlaps flag propagation) ----
        const int erow = x[b * SS + s];                 // x is [B][S]
        const float* eb = embed + (size_t)erow * DD + quad * 8;
        #pragma unroll
        for (int kt = 0; kt < 16; ++kt) {
            const float4 e0 = *(const float4*)(eb + kt * 32);
            const float4 e1 = *(const float4*)(eb + kt * 32 + 4);
            const float ev[8] = {e0.x, e0.y, e0.z, e0.w, e1.x, e1.y, e1.z, e1.w};
            short8 xhi, xlo;
            #pragma unroll
            for (int j = 0; j < 8; ++j) {
                const unsigned hib = f2bf_bits(ev[j]);
                const float hif = __builtin_bit_cast(float, hib << 16);
                const unsigned lob = f2bf_bits(ev[j] - hif);
                xhi[j] = (short)hib;
                xlo[j] = (short)lob;
            }
            const short8 whi = wlds[(0 * 32 + kt) * 64 + lane];
            const short8 wlo = wlds[(1 * 32 + kt) * 64 + lane];
            acc = __builtin_amdgcn_mfma_f32_16x16x32_bf16(whi, xhi, acc, 0, 0, 0);
            acc = __builtin_amdgcn_mfma_f32_16x16x32_bf16(whi, xlo, acc, 0, 0, 0);
            acc = __builtin_amdgcn_mfma_f32_16x16x32_bf16(wlo, xhi, acc, 0, 0, 0);
        }

        // ---------- wait: all WGs of this dir finished step t-1 ----------
        if (t > 0) {
            const unsigned tgt = (unsigned)t;
            unsigned va, vb;
            do {
                va = __hip_atomic_load(myflg + lane, __ATOMIC_RELAXED,
                                       __HIP_MEMORY_SCOPE_AGENT);
                vb = __hip_atomic_load(myflg + 64 + lane, __ATOMIC_RELAXED,
                                       __HIP_MEMORY_SCOPE_AGENT);
            } while (__any(va < tgt || vb < tgt));
            asm volatile("" ::: "memory");
        }

        // ---------- h-part: agent-scope 8B loads from L3 ----------
        const size_t zrow = ((size_t)(p * 2 + dir) * BB + b) * HH + quad * 8;
        const unsigned long long* zhq =
            (const unsigned long long*)(hspl + zrow);
        const unsigned long long* zlq =
            (const unsigned long long*)(hspl + HSPL_PLANE + zrow);
        #pragma unroll
        for (int kt = 0; kt < 16; ++kt) {
            union { unsigned long long q[2]; short8 v; } uh, ul;
            uh.q[0] = __hip_atomic_load(zhq + kt * 8 + 0, __ATOMIC_RELAXED,
                                        __HIP_MEMORY_SCOPE_AGENT);
            uh.q[1] = __hip_atomic_load(zhq + kt * 8 + 1, __ATOMIC_RELAXED,
                                        __HIP_MEMORY_SCOPE_AGENT);
            ul.q[0] = __hip_atomic_load(zlq + kt * 8 + 0, __ATOMIC_RELAXED,
                                        __HIP_MEMORY_SCOPE_AGENT);
            ul.q[1] = __hip_atomic_load(zlq + kt * 8 + 1, __ATOMIC_RELAXED,
                                        __HIP_MEMORY_SCOPE_AGENT);
            const short8 zhi = uh.v;
            const short8 zlo = ul.v;
            const short8 whi = wlds[(0 * 32 + 16 + kt) * 64 + lane];
            const short8 wlo = wlds[(1 * 32 + 16 + kt) * 64 + lane];
            acc = __builtin_amdgcn_mfma_f32_16x16x32_bf16(whi, zhi, acc, 0, 0, 0);
            acc = __builtin_amdgcn_mfma_f32_16x16x32_bf16(whi, zlo, acc, 0, 0, 0);
            acc = __builtin_amdgcn_mfma_f32_16x16x32_bf16(wlo, zhi, acc, 0, 0, 0);
        }

        // ---------- bias + per-wave exchange (identical to R3) ----------
        #pragma unroll
        for (int r2 = 0; r2 < 4; ++r2)
            exw[(quad * 4 + r2) * 16 + nn] = acc[r2] + bias_arr[r2];
        float pg[4];
        #pragma unroll
        for (int g = 0; g < 4; ++g)
            pg[g] = exw[(g * 4 + quad) * 16 + nn];

        const float f_  = 1.f / (1.f + expf(-pg[0]));
        const float i_  = 1.f / (1.f + expf(-pg[1]));
        const float ct  = tanhf(pg[2]);
        const float o_  = 1.f / (1.f + expf(-pg[3]));
        const float c_  = (f_ + i_) * ct;      // faithful: prev cell unused
        const float hn  = o_ * tanhf(c_);

        // stage split h in LDS; hist store (normal, consumed post-kernel)
        const unsigned hib = f2bf_bits(hn);
        const float hif = __builtin_bit_cast(float, hib << 16);
        const unsigned lob = f2bf_bits(hn - hif);
        stg[(0 * 4 + quad) * 64 + b] = (unsigned short)hib;
        stg[(1 * 4 + quad) * 64 + b] = (unsigned short)lob;
        hist[(((size_t)dir * SS + s) * HH + h) * BB + b] = hn;
        __syncthreads();

        // ---------- publish: packed dword write-through stores ----------
        {
            const int plane = tid >> 7;          // 0 hi, 1 lo
            const int d     = tid & 127;
            const int pb    = d >> 1;
            const int pair  = d & 1;
            const unsigned v0 = stg[(plane * 4 + pair * 2 + 0) * 64 + pb];
            const unsigned v1 = stg[(plane * 4 + pair * 2 + 1) * 64 + pb];
            const unsigned val = v0 | (v1 << 16);
            const size_t soff = ((size_t)((p ^ 1) * 2 + dir) * BB + pb) * HH
                                + h0 + pair * 2;
            unsigned* dst = (unsigned*)(hspl + (size_t)plane * HSPL_PLANE + soff);
            __hip_atomic_store(dst, val, __ATOMIC_RELAXED,
                               __HIP_MEMORY_SCOPE_AGENT);
        }
        asm volatile("s_waitcnt vmcnt(0)" ::: "memory");
        __syncthreads();
        if (tid == 0)
            __hip_atomic_store(myflg + wlocal, (unsigned)(t + 1),
                               __ATOMIC_RELAXED, __HIP_MEMORY_SCOPE_AGENT);
    }
}

// ---------------------------------------------------------------------------
__global__ __launch_bounds__(256)
void pool_k(const float* __restrict__ hist, float* __restrict__ pooled)
{
    const int i = blockIdx.x * 256 + threadIdx.x;   // i = h*64 + b
    float m = -2.0f;
    for (int s = 0; s < SS; ++s) {
        const float a = hist[(size_t)s * (HH * BB) + i];
        const float c = hist[(size_t)(SS + s) * (HH * BB) + i];
        m = fmaxf(m, tanhf(a * c));
    }
    pooled[i] = m;
}

__global__ __launch_bounds__(256)
void outgemm_k(const float* __restrict__ pooled, const float* __restrict__ Wout,
               const float* __restrict__ bout, float* __restrict__ out)
{
    const int c   = blockIdx.x;
    const int tid = threadIdx.x;
    const int b   = tid & 63;
    const int q   = __builtin_amdgcn_readfirstlane(tid >> 6);
    float p = 0.0f;
    for (int j = 0; j < 128; ++j) {
        const int h = q * 128 + j;
        p = fmaf(pooled[(size_t)h * BB + b], Wout[c * HH + h], p);
    }
    __shared__ float red[4][BB];
    red[q][b] = p;
    __syncthreads();
    if (tid < BB)
        out[tid * CC + c] = red[0][tid] + red[1][tid] + red[2][tid] + red[3][tid] + bout[c];
}

// ---------------------------------------------------------------------------
extern "C" void kernel_launch(void* const* d_in, const int* in_sizes, int n_in,
                              void* d_out, int out_size, void* d_ws, size_t ws_size,
                              hipStream_t stream)
{
    const int*   x     = (const int*)d_in[0];
    const float* embed = (const float*)d_in[1];
    const float* fwd_W = (const float*)d_in[2];
    const float* fwd_b = (const float*)d_in[3];
    const float* bwd_W = (const float*)d_in[4];
    const float* bwd_b = (const float*)d_in[5];
    const float* Wout  = (const float*)d_in[6];
    const float* bout  = (const float*)d_in[7];
    float* out = (float*)d_out;

    char* wsb = (char*)d_ws;
    short*    wfrag  = (short*)(wsb + OFF_WFRAG);
    short*    hspl   = (short*)(wsb + OFF_HSPL);
    unsigned* flg    = (unsigned*)(wsb + OFF_FLG);
    float*    hist   = (float*)(wsb + OFF_HIST);
    float*    pooled = (float*)(wsb + OFF_POOLED);

    wpack_k<<<256, 256, 0, stream>>>(fwd_W, bwd_W, wfrag);
    // zero hspl + flags (contiguous region)
    zero_k<<<512, 256, 0, stream>>>((unsigned*)(wsb + OFF_HSPL),
                                    (int)((SZ_HSPL + 1024) / 4));

    hipFuncSetAttribute((const void*)bilstm_recur_k,
                        hipFuncAttributeMaxDynamicSharedMemorySize, 70656);
    void* args[] = {(void*)&x, (void*)&embed, (void*)&fwd_b, (void*)&bwd_b,
                    (void*)&wfrag, (void*)&hspl, (void*)&hist, (void*)&flg};
    hipLaunchCooperativeKernel((void*)bilstm_recur_k, dim3(256), dim3(256),
                               args, 70656, stream);

    pool_k<<<128, 256, 0, stream>>>(hist, pooled);
    outgemm_k<<<CC, 256, 0, stream>>>(pooled, Wout, bout, out);
}

// Round 8
// 3356.669 us; speedup vs baseline: 6.0841x; 1.0697x over previous
//
#include <hip/hip_runtime.h>
#include <math.h>

#define HH 512
#define DD 512
#define BB 64
#define SS 256
#define KK 1024
#define CC 5

typedef __attribute__((ext_vector_type(8))) short short8;
typedef __attribute__((ext_vector_type(4))) float float4v;

// ---- workspace layout (bytes) ----  total 101,188,608 B
#define OFF_XEF     0u               // 256 s x 2 sp x 64 b x 512 k shorts = 33.5 MB
#define OFF_HSPL    33554432u        // [2 sp][2 phase][2 dir][64 b][512 k] shorts
#define OFF_FLG     34078720u        // 256 x 4B flags
#define OFF_HIST    34079744u        // 2 x 256 x 512 x 64 fp32 = 67 MB
#define OFF_POOLED  OFF_HSPL         // pooled overlays hspl (dead after recurrence)
#define HSPL_PLANE  131072           // shorts per split plane

__device__ __forceinline__ unsigned f2bf_bits(float f) {
    unsigned u = __builtin_bit_cast(unsigned, f);
    return (u + 0x7fffu + ((u >> 16) & 1u)) >> 16;   // RNE
}
__device__ __forceinline__ float sigm_(float v) {
    return 1.f / (1.f + expf(-v));
}
__device__ __forceinline__ float tanh_(float v) {
    return tanhf(v);
}

// ---------------------------------------------------------------------------
// Gather embeddings + split hi/lo bf16 into xef[s][sp][b][k].
// ---------------------------------------------------------------------------
__global__ __launch_bounds__(256)
void gather_split_k(const int* __restrict__ x, const float* __restrict__ embed,
                    short* __restrict__ xef)
{
    const int s   = blockIdx.x;
    const int tid = threadIdx.x;
    const int b   = tid & 63;
    const int seg = tid >> 6;            // 4 segs x 128 k
    __shared__ int rows[BB];
    if (tid < BB) rows[tid] = x[tid * SS + s];   // x is [B][S]
    __syncthreads();
    const float* e = embed + (size_t)rows[b] * DD + seg * 128;
    short* oh = xef + ((size_t)(s * 2 + 0) * BB + b) * 512 + seg * 128;
    short* ol = xef + ((size_t)(s * 2 + 1) * BB + b) * 512 + seg * 128;
    for (int k0 = 0; k0 < 128; k0 += 8) {
        const float4 a = *(const float4*)(e + k0);
        const float4 c = *(const float4*)(e + k0 + 4);
        const float ev[8] = {a.x, a.y, a.z, a.w, c.x, c.y, c.z, c.w};
        short8 vh, vl;
        #pragma unroll
        for (int j = 0; j < 8; ++j) {
            const unsigned hib = f2bf_bits(ev[j]);
            const float hif = __builtin_bit_cast(float, hib << 16);
            const unsigned lob = f2bf_bits(ev[j] - hif);
            vh[j] = (short)hib;
            vl[j] = (short)lob;
        }
        *(short8*)(oh + k0) = vh;
        *(short8*)(ol + k0) = vl;
    }
}

// ---------------------------------------------------------------------------
__global__ __launch_bounds__(256)
void zero_k(unsigned* __restrict__ base, int ndw)
{
    int i = blockIdx.x * 256 + threadIdx.x;
    const int stride = gridDim.x * 256;
    for (; i < ndw; i += stride) base[i] = 0u;
}

// ---------------------------------------------------------------------------
// Cooperative recurrence: 256 WGs x 256 thr (1 WG/CU). Plain t-loop (R4
// control flow). x-fragments read from xef IN-LOOP (no cross-step register
// prefetch — R5/6/7's rotation construct is the bisection suspect).
// ---------------------------------------------------------------------------
__global__ void __launch_bounds__(256, 1)
bilstm_recur_k(const short* __restrict__ xef,
               const float* __restrict__ fwd_W, const float* __restrict__ bwd_W,
               const float* __restrict__ fwd_b, const float* __restrict__ bwd_b,
               short* __restrict__ hspl, float* __restrict__ hist,
               unsigned* __restrict__ flg)
{
    extern __shared__ char smem[];
    short8* wlds = (short8*)smem;                          // 64 KB W fragments
    float*  ex   = (float*)(smem + 65536);                 // 4 KB exchange
    unsigned short* stg = (unsigned short*)(smem + 69632); // 1 KB publish stage

    const int w      = blockIdx.x;
    const int dir    = w >> 7;
    const int wlocal = w & 127;
    const int h0     = wlocal << 2;
    const int tid    = threadIdx.x;
    const int lane   = tid & 63;
    const int wv     = __builtin_amdgcn_readfirstlane(tid >> 6);
    const int n0     = wv << 4;
    const int nn     = lane & 15;
    const int quad   = lane >> 4;

    // ---- pack this WG's W fragments straight into LDS (bit-identical to
    //      wpack_k: f2bf_bits split of W[(g*H+h0+hh)][kt*32+quad*8+j]) ----
    {
        const float* W = dir ? bwd_W : fwd_W;
        const int m  = lane & 15;
        const int g  = m >> 2;
        const int hh = m & 3;
        const float* wrow = W + ((size_t)g * HH + h0 + hh) * KK + quad * 8;
        for (int kk = 0; kk < 8; ++kk) {
            const int kt = wv * 8 + kk;          // 4 waves x 8 = 32 kt
            const float4 a  = *(const float4*)(wrow + kt * 32);
            const float4 c4 = *(const float4*)(wrow + kt * 32 + 4);
            const float ev[8] = {a.x, a.y, a.z, a.w, c4.x, c4.y, c4.z, c4.w};
            short8 vh, vl;
            #pragma unroll
            for (int j = 0; j < 8; ++j) {
                const unsigned hib = f2bf_bits(ev[j]);
                const float hif = __builtin_bit_cast(float, hib << 16);
                const unsigned lob = f2bf_bits(ev[j] - hif);
                vh[j] = (short)hib;
                vl[j] = (short)lob;
            }
            wlds[(0 * 32 + kt) * 64 + lane] = vh;
            wlds[(1 * 32 + kt) * 64 + lane] = vl;
        }
    }
    __syncthreads();

    const float* bi = dir ? bwd_b : fwd_b;
    const float4 biasv = *(const float4*)(bi + quad * HH + h0);
    const float bias_arr[4] = {biasv.x, biasv.y, biasv.z, biasv.w};

    unsigned* myflg = flg + dir * 128;
    float* exw = ex + wv * 256;
    const int b = n0 + nn;
    const int h = h0 + quad;

    for (int t = 0; t < SS; ++t) {
        const int s = dir ? (SS - 1 - t) : t;
        const int p = t & 1;

        float4v acc = {0.f, 0.f, 0.f, 0.f};

        // ---------- x-part: contiguous fragment loads from xef ----------
        {
            const short8* xh8 = (const short8*)(xef +
                ((size_t)(s * 2 + 0) * BB + b) * 512 + quad * 8);
            const short8* xl8 = (const short8*)(xef +
                ((size_t)(s * 2 + 1) * BB + b) * 512 + quad * 8);
            #pragma unroll
            for (int kt = 0; kt < 16; ++kt) {
                const short8 xh  = xh8[kt * 4];
                const short8 xl  = xl8[kt * 4];
                const short8 whi = wlds[(0 * 32 + kt) * 64 + lane];
                const short8 wlo = wlds[(1 * 32 + kt) * 64 + lane];
                acc = __builtin_amdgcn_mfma_f32_16x16x32_bf16(whi, xh, acc, 0, 0, 0);
                acc = __builtin_amdgcn_mfma_f32_16x16x32_bf16(whi, xl, acc, 0, 0, 0);
                acc = __builtin_amdgcn_mfma_f32_16x16x32_bf16(wlo, xh, acc, 0, 0, 0);
            }
        }

        // ---------- wait: all WGs of this dir finished step t-1 ----------
        if (t > 0) {
            const unsigned tgt = (unsigned)t;
            unsigned va, vb;
            do {
                va = __hip_atomic_load(myflg + lane, __ATOMIC_RELAXED,
                                       __HIP_MEMORY_SCOPE_AGENT);
                vb = __hip_atomic_load(myflg + 64 + lane, __ATOMIC_RELAXED,
                                       __HIP_MEMORY_SCOPE_AGENT);
            } while (__any(va < tgt || vb < tgt));
            asm volatile("" ::: "memory");
        }

        // ---------- h-part: agent-scope 8B loads ----------
        {
            const size_t zrow = ((size_t)(p * 2 + dir) * BB + b) * HH + quad * 8;
            const unsigned long long* zhq = (const unsigned long long*)(hspl + zrow);
            const unsigned long long* zlq =
                (const unsigned long long*)(hspl + HSPL_PLANE + zrow);
            #pragma unroll
            for (int kt = 0; kt < 16; ++kt) {
                union { unsigned long long q[2]; short8 v; } uh, ul;
                uh.q[0] = __hip_atomic_load(zhq + kt * 8 + 0, __ATOMIC_RELAXED,
                                            __HIP_MEMORY_SCOPE_AGENT);
                uh.q[1] = __hip_atomic_load(zhq + kt * 8 + 1, __ATOMIC_RELAXED,
                                            __HIP_MEMORY_SCOPE_AGENT);
                ul.q[0] = __hip_atomic_load(zlq + kt * 8 + 0, __ATOMIC_RELAXED,
                                            __HIP_MEMORY_SCOPE_AGENT);
                ul.q[1] = __hip_atomic_load(zlq + kt * 8 + 1, __ATOMIC_RELAXED,
                                            __HIP_MEMORY_SCOPE_AGENT);
                const short8 whi = wlds[(0 * 32 + 16 + kt) * 64 + lane];
                const short8 wlo = wlds[(1 * 32 + 16 + kt) * 64 + lane];
                acc = __builtin_amdgcn_mfma_f32_16x16x32_bf16(whi, uh.v, acc, 0, 0, 0);
                acc = __builtin_amdgcn_mfma_f32_16x16x32_bf16(whi, ul.v, acc, 0, 0, 0);
                acc = __builtin_amdgcn_mfma_f32_16x16x32_bf16(wlo, uh.v, acc, 0, 0, 0);
            }
        }

        // ---------- bias + per-wave exchange ----------
        #pragma unroll
        for (int r2 = 0; r2 < 4; ++r2)
            exw[(quad * 4 + r2) * 16 + nn] = acc[r2] + bias_arr[r2];
        float pg[4];
        #pragma unroll
        for (int g_ = 0; g_ < 4; ++g_)
            pg[g_] = exw[(g_ * 4 + quad) * 16 + nn];

        const float f_  = sigm_(pg[0]);
        const float i_  = sigm_(pg[1]);
        const float ct  = tanh_(pg[2]);
        const float o_  = sigm_(pg[3]);
        const float c_  = (f_ + i_) * ct;      // faithful: prev cell unused
        const float hn  = o_ * tanh_(c_);

        const unsigned hib = f2bf_bits(hn);
        const float hif = __builtin_bit_cast(float, hib << 16);
        const unsigned lob = f2bf_bits(hn - hif);
        stg[(0 * 4 + quad) * 64 + b] = (unsigned short)hib;
        stg[(1 * 4 + quad) * 64 + b] = (unsigned short)lob;
        hist[(((size_t)dir * SS + s) * HH + h) * BB + b] = hn;
        __syncthreads();

        // ---------- publish: packed dword write-through stores ----------
        {
            const int plane = tid >> 7;          // 0 hi, 1 lo
            const int d     = tid & 127;
            const int pb    = d >> 1;
            const int pair  = d & 1;
            const unsigned v0 = stg[(plane * 4 + pair * 2 + 0) * 64 + pb];
            const unsigned v1 = stg[(plane * 4 + pair * 2 + 1) * 64 + pb];
            const unsigned val = v0 | (v1 << 16);
            const size_t soff = ((size_t)((p ^ 1) * 2 + dir) * BB + pb) * HH
                                + h0 + pair * 2;
            unsigned* dst = (unsigned*)(hspl + (size_t)plane * HSPL_PLANE + soff);
            __hip_atomic_store(dst, val, __ATOMIC_RELAXED,
                               __HIP_MEMORY_SCOPE_AGENT);
        }
        asm volatile("s_waitcnt vmcnt(0)" ::: "memory");
        __syncthreads();
        if (tid == 0)
            __hip_atomic_store(myflg + wlocal, (unsigned)(t + 1),
                               __ATOMIC_RELAXED, __HIP_MEMORY_SCOPE_AGENT);
    }
}

// ---------------------------------------------------------------------------
__global__ __launch_bounds__(256)
void pool_k(const float* __restrict__ hist, float* __restrict__ pooled)
{
    const int i = blockIdx.x * 256 + threadIdx.x;   // i = h*64 + b
    float m = -2.0f;
    for (int s = 0; s < SS; ++s) {
        const float a = hist[(size_t)s * (HH * BB) + i];
        const float c = hist[(size_t)(SS + s) * (HH * BB) + i];
        m = fmaxf(m, tanhf(a * c));
    }
    pooled[i] = m;
}

__global__ __launch_bounds__(256)
void outgemm_k(const float* __restrict__ pooled, const float* __restrict__ Wout,
               const float* __restrict__ bout, float* __restrict__ out)
{
    const int c   = blockIdx.x;
    const int tid = threadIdx.x;
    const int b   = tid & 63;
    const int q   = __builtin_amdgcn_readfirstlane(tid >> 6);
    float p = 0.0f;
    for (int j = 0; j < 128; ++j) {
        const int h = q * 128 + j;
        p = fmaf(pooled[(size_t)h * BB + b], Wout[c * HH + h], p);
    }
    __shared__ float red[4][BB];
    red[q][b] = p;
    __syncthreads();
    if (tid < BB)
        out[tid * CC + c] = red[0][tid] + red[1][tid] + red[2][tid] + red[3][tid] + bout[c];
}

// ---------------------------------------------------------------------------
extern "C" void kernel_launch(void* const* d_in, const int* in_sizes, int n_in,
                              void* d_out, int out_size, void* d_ws, size_t ws_size,
                              hipStream_t stream)
{
    const int*   x     = (const int*)d_in[0];
    const float* embed = (const float*)d_in[1];
    const float* fwd_W = (const float*)d_in[2];
    const float* fwd_b = (const float*)d_in[3];
    const float* bwd_W = (const float*)d_in[4];
    const float* bwd_b = (const float*)d_in[5];
    const float* Wout  = (const float*)d_in[6];
    const float* bout  = (const float*)d_in[7];
    float* out = (float*)d_out;

    char* wsb = (char*)d_ws;
    short*    xef    = (short*)(wsb + OFF_XEF);
    short*    hspl   = (short*)(wsb + OFF_HSPL);
    unsigned* flg    = (unsigned*)(wsb + OFF_FLG);
    float*    hist   = (float*)(wsb + OFF_HIST);
    float*    pooled = (float*)(wsb + OFF_POOLED);   // overlays hspl (dead)

    gather_split_k<<<SS, 256, 0, stream>>>(x, embed, xef);
    zero_k<<<512, 256, 0, stream>>>((unsigned*)(wsb + OFF_HSPL),
                                    (int)((524288 + 1024) / 4));

    hipFuncSetAttribute((const void*)bilstm_recur_k,
                        hipFuncAttributeMaxDynamicSharedMemorySize, 70656);
    void* args[] = {(void*)&xef, (void*)&fwd_W, (void*)&bwd_W,
                    (void*)&fwd_b, (void*)&bwd_b,
                    (void*)&hspl, (void*)&hist, (void*)&flg};
    hipLaunchCooperativeKernel((void*)bilstm_recur_k, dim3(256), dim3(256),
                               args, 70656, stream);

    pool_k<<<128, 256, 0, stream>>>(hist, pooled);
    outgemm_k<<<CC, 256, 0, stream>>>(pooled, Wout, bout, out);
}